// Round 21
// baseline (136.207 us; speedup 1.0000x reference)
//
#include <hip/hip_runtime.h>
#include <math.h>

#define N_NODES 50000
#define N_EDGES 800000
#define EMBED 256
#define HID 128
#define OUTD 12
#define N_TGT 4096

#define SCAN_NB 196   // ceil(50000/256)
#define NPART 8       // XCD count; blockIdx&7 ~ XCD id (round-robin dispatch)
#define NODES_PER_PART 6250  // 50000/8
#define RCAP 64       // padded-CSR row capacity
#define NB_G1 782     // gemm blocks = ceil(50000/64)
#define NB_FILLB 6256 // fill blocks = ceil(200000/256)*8

typedef short bf16x8 __attribute__((ext_vector_type(8)));
typedef float f32x4 __attribute__((ext_vector_type(4)));
typedef int intx4 __attribute__((ext_vector_type(4)));

// f32 -> bf16 round-to-nearest-even (bit-exact, deterministic)
__device__ __forceinline__ unsigned short f2b(float f) {
    union { float f; unsigned int u; } v;
    v.f = f;
    unsigned int u = v.u;
    return (unsigned short)((u + 0x7FFFu + ((u >> 16) & 1u)) >> 16);
}

__device__ __forceinline__ float b2f(unsigned short s) {
    union { unsigned int u; float f; } v;
    v.u = ((unsigned int)s) << 16;
    return v.f;
}

// ---------------- prelude: zero counts + convert both weight matrices ----------------
__global__ __launch_bounds__(256) void k_prelude(int* __restrict__ counts,
                                                 const float* __restrict__ W1,
                                                 unsigned short* __restrict__ Wt1,
                                                 const float* __restrict__ W2,
                                                 unsigned short* __restrict__ Wt2) {
    int i = blockIdx.x * 256 + threadIdx.x;     // grid 196*256 = 50176
    if (i < N_NODES) counts[i] = 0;
    if (i < 32768) {                            // Wt1: 128 x 256
        int nn = i >> 8, k = i & 255;
        Wt1[nn * 256 + k] = f2b(W1[(size_t)k * 128 + nn]);
    } else if (i < 49152) {                     // Wt2: 128 x 128
        int j = i - 32768;
        int nn = j >> 7, k = j & 127;
        Wt2[nn * 128 + k] = f2b(W2[(size_t)k * 128 + nn]);
    }
}

// ---------------- gemm body (shared by fused1 and gemm2) ----------------
template <int K, bool IS_BF16>
__device__ __forceinline__ void gemm_body(int gb, int tid, const void* __restrict__ Xv,
                                          const unsigned short* __restrict__ Wt,
                                          unsigned short* __restrict__ Hb, int n,
                                          unsigned short* As /*64*40 LDS*/) {
    const int row0 = gb * 64;
    const int w = tid >> 6, lane = tid & 63;
    const int lr = lane & 15, lg = lane >> 4;
    constexpr int NKS = K / 32;

    bf16x8 bfr[NKS][2];
#pragma unroll
    for (int ks = 0; ks < NKS; ++ks)
#pragma unroll
        for (int fn = 0; fn < 2; ++fn) {
            int colg = w * 32 + fn * 16 + lr;
            bfr[ks][fn] = *(const bf16x8*)&Wt[(size_t)colg * K + ks * 32 + lg * 8];
        }

    const int r0s = (tid * 2) >> 3, c0s = ((tid * 2) & 7) * 4;
    const int r1s = (tid * 2 + 1) >> 3, c1s = ((tid * 2 + 1) & 7) * 4;

    const float* Xf = (const float*)Xv;
    const unsigned short* Xb = (const unsigned short*)Xv;

    float4 f0 = make_float4(0.f, 0.f, 0.f, 0.f), f1 = f0;
    ushort4 u0 = make_ushort4(0, 0, 0, 0), u1 = u0;
    if (IS_BF16) {
        if (row0 + r0s < n) u0 = *(const ushort4*)&Xb[(size_t)(row0 + r0s) * K + c0s];
        if (row0 + r1s < n) u1 = *(const ushort4*)&Xb[(size_t)(row0 + r1s) * K + c1s];
    } else {
        if (row0 + r0s < n) f0 = *(const float4*)&Xf[(size_t)(row0 + r0s) * K + c0s];
        if (row0 + r1s < n) f1 = *(const float4*)&Xf[(size_t)(row0 + r1s) * K + c1s];
    }

    f32x4 acc[4][2] = {};
#pragma unroll
    for (int ks = 0; ks < NKS; ++ks) {
        __syncthreads();
        if (IS_BF16) {
            *(ushort4*)&As[r0s * 40 + c0s] = u0;
            *(ushort4*)&As[r1s * 40 + c1s] = u1;
        } else {
            *(ushort4*)&As[r0s * 40 + c0s] = make_ushort4(f2b(f0.x), f2b(f0.y), f2b(f0.z), f2b(f0.w));
            *(ushort4*)&As[r1s * 40 + c1s] = make_ushort4(f2b(f1.x), f2b(f1.y), f2b(f1.z), f2b(f1.w));
        }
        __syncthreads();
        if (ks + 1 < NKS) {
            int ko = (ks + 1) * 32;
            if (IS_BF16) {
                u0 = make_ushort4(0, 0, 0, 0); u1 = u0;
                if (row0 + r0s < n) u0 = *(const ushort4*)&Xb[(size_t)(row0 + r0s) * K + ko + c0s];
                if (row0 + r1s < n) u1 = *(const ushort4*)&Xb[(size_t)(row0 + r1s) * K + ko + c1s];
            } else {
                f0 = make_float4(0.f, 0.f, 0.f, 0.f); f1 = f0;
                if (row0 + r0s < n) f0 = *(const float4*)&Xf[(size_t)(row0 + r0s) * K + ko + c0s];
                if (row0 + r1s < n) f1 = *(const float4*)&Xf[(size_t)(row0 + r1s) * K + ko + c1s];
            }
        }
#pragma unroll
        for (int fm = 0; fm < 4; ++fm) {
            bf16x8 afr = *(const bf16x8*)&As[(fm * 16 + lr) * 40 + lg * 8];
#pragma unroll
            for (int fn = 0; fn < 2; ++fn)
                acc[fm][fn] = __builtin_amdgcn_mfma_f32_16x16x32_bf16(
                    afr, bfr[ks][fn], acc[fm][fn], 0, 0, 0);
        }
    }
#pragma unroll
    for (int fm = 0; fm < 4; ++fm) {
#pragma unroll
        for (int r = 0; r < 4; ++r) {
            int gr = row0 + fm * 16 + lg * 4 + r;
            if (gr < n) {
#pragma unroll
                for (int fn = 0; fn < 2; ++fn)
                    Hb[(size_t)gr * 128 + w * 32 + fn * 16 + lr] = f2b(acc[fm][fn][r]);
            }
        }
    }
}

// ---------------- fused: padded-CSR fill (blocks 0..NB_FILLB) || gemm1 (rest) ----------------
// FILL FIRST: the fill is the long pole (L2-atomic throughput, ~1/cyc/XCD); dispatching
// its blocks first saturates the atomic pipeline at t=0 while gemm blocks backfill
// the idle VALU/MFMA slots behind it.
__global__ __launch_bounds__(256) void k_fused1(const float* __restrict__ x,
                                                const unsigned short* __restrict__ Wt1,
                                                unsigned short* __restrict__ bufA,
                                                const int* __restrict__ src,
                                                const int* __restrict__ dst,
                                                int* __restrict__ counts,
                                                int* __restrict__ col_p, int nE4) {
    __shared__ unsigned short As[64 * 40];
    const int b = blockIdx.x, tid = threadIdx.x;
    if (b >= NB_FILLB) {
        gemm_body<EMBED, false>(b - NB_FILLB, tid, x, Wt1, bufA, N_NODES, As);
        return;
    }
    int g = b & (NPART - 1);
    int i = (b >> 3) * 256 + tid;
    if (i >= nE4) return;
    intx4 d4 = *(const intx4*)&dst[i * 4];
    intx4 s4 = *(const intx4*)&src[i * 4];
#pragma unroll
    for (int q = 0; q < 4; ++q) {
        int d = d4[q];
        if ((unsigned)(d - g * NODES_PER_PART) < (unsigned)NODES_PER_PART) {
            int pos = atomicAdd(&counts[d], 1);
            if (pos < RCAP) col_p[d * RCAP + pos] = s4[q];
        }
    }
}

// gemm2 standalone
__global__ __launch_bounds__(256) void k_gemm2(const unsigned short* __restrict__ X,
                                               const unsigned short* __restrict__ Wt,
                                               unsigned short* __restrict__ Hb, int n) {
    __shared__ unsigned short As[64 * 40];
    gemm_body<HID, true>(blockIdx.x, threadIdx.x, X, Wt, Hb, n, As);
}

// ---------------- 64-lane bitonic sort of one padded row -> LDS ----------------
// col_p stays unsorted globally; every reader sorts identically (comparison sort on
// the same multiset -> identical sorted keys) => FP sum order deterministic.
__device__ __forceinline__ void sort_row_to_lds(const int* __restrict__ col_p,
                                                int v, int cnt, int lane64,
                                                int* __restrict__ srow) {
    int key = 0x7FFFFFFF;
    if (lane64 < cnt) key = col_p[v * RCAP + lane64];
#pragma unroll
    for (int k = 2; k <= 64; k <<= 1) {
#pragma unroll
        for (int j = k >> 1; j > 0; j >>= 1) {
            int other = __shfl_xor(key, j);
            bool up = ((lane64 & k) == 0);
            bool lower = ((lane64 & j) == 0);
            key = (lower == up) ? min(key, other) : max(key, other);
        }
    }
    srow[lane64] = key;
}

// ---------------- shared agg core: LDS col row, on-the-fly dinv ----------------
__device__ __forceinline__ f32x4 agg_core(const unsigned short* __restrict__ h,
                                          const int* __restrict__ counts,
                                          const int* __restrict__ srow,
                                          int v, int cnt, int lane, float dv) {
    ushort4 hv = *(const ushort4*)&h[(size_t)v * HID + lane * 4];
    float sl = dv * dv;
    f32x4 a0 = {b2f(hv.x) * sl, b2f(hv.y) * sl, b2f(hv.z) * sl, b2f(hv.w) * sl};
    f32x4 a1 = {0.f, 0.f, 0.f, 0.f}, a2 = a1, a3 = a1;
    for (int j0 = 0; j0 < cnt; j0 += 32) {
        int m = cnt - j0; if (m > 32) m = 32;
        int sj = 0; float wj = 0.f;                 // lanes >= m: w=0 -> exact no-op FMA
        if (lane < m) {
            sj = srow[j0 + lane];                   // LDS (sorted)
            wj = rsqrtf(1.0f + (float)counts[sj]) * dv;
        }
        int M = (m + 3) & ~3;
        float w0 = __shfl(wj, 0, 32), w1 = __shfl(wj, 1, 32);
        float w2 = __shfl(wj, 2, 32), w3 = __shfl(wj, 3, 32);
        int s0 = __shfl(sj, 0, 32), s1 = __shfl(sj, 1, 32);
        int s2 = __shfl(sj, 2, 32), s3 = __shfl(sj, 3, 32);
        ushort4 q0 = *(const ushort4*)&h[(size_t)s0 * HID + lane * 4];
        ushort4 q1 = *(const ushort4*)&h[(size_t)s1 * HID + lane * 4];
        ushort4 q2 = *(const ushort4*)&h[(size_t)s2 * HID + lane * 4];
        ushort4 q3 = *(const ushort4*)&h[(size_t)s3 * HID + lane * 4];
        for (int jj = 0; jj < M; jj += 4) {
            ushort4 n0 = q0, n1 = q1, n2 = q2, n3 = q3;
            float nw0 = 0.f, nw1 = 0.f, nw2 = 0.f, nw3 = 0.f;
            if (jj + 4 < M) {
                int t0 = __shfl(sj, jj + 4, 32), t1 = __shfl(sj, jj + 5, 32);
                int t2 = __shfl(sj, jj + 6, 32), t3 = __shfl(sj, jj + 7, 32);
                nw0 = __shfl(wj, jj + 4, 32); nw1 = __shfl(wj, jj + 5, 32);
                nw2 = __shfl(wj, jj + 6, 32); nw3 = __shfl(wj, jj + 7, 32);
                n0 = *(const ushort4*)&h[(size_t)t0 * HID + lane * 4];
                n1 = *(const ushort4*)&h[(size_t)t1 * HID + lane * 4];
                n2 = *(const ushort4*)&h[(size_t)t2 * HID + lane * 4];
                n3 = *(const ushort4*)&h[(size_t)t3 * HID + lane * 4];
            }
            a0[0] = fmaf(b2f(q0.x), w0, a0[0]); a0[1] = fmaf(b2f(q0.y), w0, a0[1]);
            a0[2] = fmaf(b2f(q0.z), w0, a0[2]); a0[3] = fmaf(b2f(q0.w), w0, a0[3]);
            a1[0] = fmaf(b2f(q1.x), w1, a1[0]); a1[1] = fmaf(b2f(q1.y), w1, a1[1]);
            a1[2] = fmaf(b2f(q1.z), w1, a1[2]); a1[3] = fmaf(b2f(q1.w), w1, a1[3]);
            a2[0] = fmaf(b2f(q2.x), w2, a2[0]); a2[1] = fmaf(b2f(q2.y), w2, a2[1]);
            a2[2] = fmaf(b2f(q2.z), w2, a2[2]); a2[3] = fmaf(b2f(q2.w), w2, a2[3]);
            a3[0] = fmaf(b2f(q3.x), w3, a3[0]); a3[1] = fmaf(b2f(q3.y), w3, a3[1]);
            a3[2] = fmaf(b2f(q3.z), w3, a3[2]); a3[3] = fmaf(b2f(q3.w), w3, a3[3]);
            q0 = n0; q1 = n1; q2 = n2; q3 = n3;
            w0 = nw0; w1 = nw1; w2 = nw2; w3 = nw3;
        }
    }
    f32x4 r;
    r[0] = (a0[0] + a1[0]) + (a2[0] + a3[0]);
    r[1] = (a0[1] + a1[1]) + (a2[1] + a3[1]);
    r[2] = (a0[2] + a1[2]) + (a2[2] + a3[2]);
    r[3] = (a0[3] + a1[3]) + (a2[3] + a3[3]);
    return r;
}

// layer-1: aggregate ALL nodes (8 nodes/block; in-kernel row sort)
__global__ __launch_bounds__(256) void k_agg_all(const unsigned short* __restrict__ h,
                                                 const int* __restrict__ counts,
                                                 const int* __restrict__ col_p,
                                                 const float* __restrict__ b,
                                                 unsigned short* __restrict__ out) {
    __shared__ int scol[8][64];
    const int tid = threadIdx.x;
    const int w = tid >> 6, lane64 = tid & 63;
    const int base = blockIdx.x * 8;
#pragma unroll
    for (int s = 0; s < 2; ++s) {
        int v = base + w * 2 + s;                       // < 50000 always (6250*8)
        int cnt = min(counts[v], RCAP);
        sort_row_to_lds(col_p, v, cnt, lane64, scol[w * 2 + s]);
    }
    __syncthreads();
    const int hw = tid >> 5, lane = tid & 31;
    const int v = base + hw;
    int cnt = min(counts[v], RCAP);
    float dv = rsqrtf(1.0f + (float)counts[v]);
    f32x4 a = agg_core(h, counts, scol[hw], v, cnt, lane, dv);
    float4 bv = *(const float4*)&b[lane * 4];
    ushort4 r;
    r.x = f2b(fmaxf(a[0] + bv.x, 0.f));
    r.y = f2b(fmaxf(a[1] + bv.y, 0.f));
    r.z = f2b(fmaxf(a[2] + bv.z, 0.f));
    r.w = f2b(fmaxf(a[3] + bv.w, 0.f));
    *(ushort4*)&out[(size_t)v * HID + lane * 4] = r;
}

// layer-2 + readout fused: 8 targets/block; in-kernel row sort; dot Wr; write pred
__global__ __launch_bounds__(256) void k_agg_tgt_final(const unsigned short* __restrict__ h,
                                                       const int* __restrict__ counts,
                                                       const int* __restrict__ col_p,
                                                       const int* __restrict__ tgt,
                                                       const float* __restrict__ b,
                                                       const float* __restrict__ Wr,
                                                       const float* __restrict__ br,
                                                       float* __restrict__ out) {
    __shared__ int scol[8][64];
    const int tid = threadIdx.x;
    const int w = tid >> 6, lane64 = tid & 63;
    const int base = blockIdx.x * 8;
#pragma unroll
    for (int s = 0; s < 2; ++s) {
        int v = tgt[base + w * 2 + s];                  // base+.. < 4096 always (512*8)
        int cnt = min(counts[v], RCAP);
        sort_row_to_lds(col_p, v, cnt, lane64, scol[w * 2 + s]);
    }
    __syncthreads();
    const int hw = tid >> 5, lane = tid & 31;
    const int tt = base + hw;
    const int v = tgt[tt];
    int cnt = min(counts[v], RCAP);
    float dv = rsqrtf(1.0f + (float)counts[v]);
    f32x4 a = agg_core(h, counts, scol[hw], v, cnt, lane, dv);
    float4 bv = *(const float4*)&b[lane * 4];
    float r0 = fmaxf(a[0] + bv.x, 0.f);
    float r1 = fmaxf(a[1] + bv.y, 0.f);
    float r2 = fmaxf(a[2] + bv.z, 0.f);
    float r3 = fmaxf(a[3] + bv.w, 0.f);
    const float* wr = &Wr[lane * 4 * OUTD];
#pragma unroll
    for (int j = 0; j < OUTD; ++j) {
        float p = r0 * wr[0 * OUTD + j] + r1 * wr[1 * OUTD + j] +
                  r2 * wr[2 * OUTD + j] + r3 * wr[3 * OUTD + j];
#pragma unroll
        for (int off = 16; off > 0; off >>= 1) p += __shfl_down(p, off, 32);
        if (lane == 0) out[tt * OUTD + j] = p + br[j];
    }
}

extern "C" void kernel_launch(void* const* d_in, const int* in_sizes, int n_in,
                              void* d_out, int out_size, void* d_ws, size_t ws_size,
                              hipStream_t stream) {
    const float* x  = (const float*)d_in[0];
    const int*   ei = (const int*)d_in[1];
    const int*   tm = (const int*)d_in[2];
    const float* W1 = (const float*)d_in[3];
    const float* b1 = (const float*)d_in[4];
    const float* W2 = (const float*)d_in[5];
    const float* b2 = (const float*)d_in[6];
    const float* Wr = (const float*)d_in[7];
    const float* br = (const float*)d_in[8];
    float* out = (float*)d_out;

    const int* e_src = ei;
    const int* e_dst = ei + N_EDGES;

    // workspace layout — all ranges disjoint:
    //   counts [0x040000, +200KB)
    //   Wt1 [0x380000)  Wt2 [0x390000)
    //   col_p [0x400000, +12.8MB)  bufA [0x1100000, +12.8MB)  bufB [0x1E00000, +12.8MB)
    char* ws = (char*)d_ws;
    int*            counts = (int*)  (ws + 0x040000);
    unsigned short* Wt1    = (unsigned short*)(ws + 0x380000);
    unsigned short* Wt2    = (unsigned short*)(ws + 0x390000);
    int*            col_p  = (int*)  (ws + 0x400000);
    unsigned short* bufA   = (unsigned short*)(ws + 0x1100000);
    unsigned short* bufB   = (unsigned short*)(ws + 0x1E00000);

    const int NE4    = N_EDGES / 4;                     // 200000
    const int NB_F1  = NB_FILLB + NB_G1;                // fill first, then gemm
    const int NB_AGG = N_NODES / 8;                     // 6250 (exact)
    const int NB_AGT = N_TGT / 8;                       // 512 (exact)

    // ---- prelude, then fused {CSR fill || gemm1} (fill blocks dispatched first) ----
    k_prelude<<<SCAN_NB, 256, 0, stream>>>(counts, W1, Wt1, W2, Wt2);
    k_fused1<<<NB_F1, 256, 0, stream>>>(x, Wt1, bufA, e_src, e_dst, counts, col_p, NE4);

    // ---- layer 1 agg (sorts rows in-kernel) ----
    k_agg_all<<<NB_AGG, 256, 0, stream>>>(bufA, counts, col_p, b1, bufB);

    // ---- layer 2 gemm, then fused {target agg + readout} ----
    k_gemm2<<<NB_G1, 256, 0, stream>>>(bufB, Wt2, bufA, N_NODES);
    k_agg_tgt_final<<<NB_AGT, 256, 0, stream>>>(bufA, counts, col_p, tm, b2, Wr, br, out);
}

// Round 22
// 130.848 us; speedup vs baseline: 1.0410x; 1.0410x over previous
//
#include <hip/hip_runtime.h>
#include <math.h>

#define N_NODES 50000
#define N_EDGES 800000
#define EMBED 256
#define HID 128
#define OUTD 12
#define N_TGT 4096

#define SCAN_NB 196   // ceil(50000/256)
#define NPART 8       // XCD count; blockIdx&7 ~ XCD id (round-robin dispatch)
#define NODES_PER_PART 6250  // 50000/8
#define RCAP 64       // padded-CSR row capacity
#define NB_G1 782     // gemm blocks = ceil(50000/64)

typedef short bf16x8 __attribute__((ext_vector_type(8)));
typedef float f32x4 __attribute__((ext_vector_type(4)));
typedef int intx4 __attribute__((ext_vector_type(4)));

// f32 -> bf16 round-to-nearest-even (bit-exact, deterministic)
__device__ __forceinline__ unsigned short f2b(float f) {
    union { float f; unsigned int u; } v;
    v.f = f;
    unsigned int u = v.u;
    return (unsigned short)((u + 0x7FFFu + ((u >> 16) & 1u)) >> 16);
}

__device__ __forceinline__ float b2f(unsigned short s) {
    union { unsigned int u; float f; } v;
    v.u = ((unsigned int)s) << 16;
    return v.f;
}

// ---------------- prelude: zero counts + convert both weight matrices ----------------
__global__ __launch_bounds__(256) void k_prelude(int* __restrict__ counts,
                                                 const float* __restrict__ W1,
                                                 unsigned short* __restrict__ Wt1,
                                                 const float* __restrict__ W2,
                                                 unsigned short* __restrict__ Wt2) {
    int i = blockIdx.x * 256 + threadIdx.x;     // grid 196*256 = 50176
    if (i < N_NODES) counts[i] = 0;
    if (i < 32768) {                            // Wt1: 128 x 256
        int nn = i >> 8, k = i & 255;
        Wt1[nn * 256 + k] = f2b(W1[(size_t)k * 128 + nn]);
    } else if (i < 49152) {                     // Wt2: 128 x 128
        int j = i - 32768;
        int nn = j >> 7, k = j & 127;
        Wt2[nn * 128 + k] = f2b(W2[(size_t)k * 128 + nn]);
    }
}

// ---------------- gemm body (shared by fused1 and gemm2) ----------------
template <int K, bool IS_BF16>
__device__ __forceinline__ void gemm_body(int gb, int tid, const void* __restrict__ Xv,
                                          const unsigned short* __restrict__ Wt,
                                          unsigned short* __restrict__ Hb, int n,
                                          unsigned short* As /*64*40 LDS*/) {
    const int row0 = gb * 64;
    const int w = tid >> 6, lane = tid & 63;
    const int lr = lane & 15, lg = lane >> 4;
    constexpr int NKS = K / 32;

    bf16x8 bfr[NKS][2];
#pragma unroll
    for (int ks = 0; ks < NKS; ++ks)
#pragma unroll
        for (int fn = 0; fn < 2; ++fn) {
            int colg = w * 32 + fn * 16 + lr;
            bfr[ks][fn] = *(const bf16x8*)&Wt[(size_t)colg * K + ks * 32 + lg * 8];
        }

    const int r0s = (tid * 2) >> 3, c0s = ((tid * 2) & 7) * 4;
    const int r1s = (tid * 2 + 1) >> 3, c1s = ((tid * 2 + 1) & 7) * 4;

    const float* Xf = (const float*)Xv;
    const unsigned short* Xb = (const unsigned short*)Xv;

    float4 f0 = make_float4(0.f, 0.f, 0.f, 0.f), f1 = f0;
    ushort4 u0 = make_ushort4(0, 0, 0, 0), u1 = u0;
    if (IS_BF16) {
        if (row0 + r0s < n) u0 = *(const ushort4*)&Xb[(size_t)(row0 + r0s) * K + c0s];
        if (row0 + r1s < n) u1 = *(const ushort4*)&Xb[(size_t)(row0 + r1s) * K + c1s];
    } else {
        if (row0 + r0s < n) f0 = *(const float4*)&Xf[(size_t)(row0 + r0s) * K + c0s];
        if (row0 + r1s < n) f1 = *(const float4*)&Xf[(size_t)(row0 + r1s) * K + c1s];
    }

    f32x4 acc[4][2] = {};
#pragma unroll
    for (int ks = 0; ks < NKS; ++ks) {
        __syncthreads();
        if (IS_BF16) {
            *(ushort4*)&As[r0s * 40 + c0s] = u0;
            *(ushort4*)&As[r1s * 40 + c1s] = u1;
        } else {
            *(ushort4*)&As[r0s * 40 + c0s] = make_ushort4(f2b(f0.x), f2b(f0.y), f2b(f0.z), f2b(f0.w));
            *(ushort4*)&As[r1s * 40 + c1s] = make_ushort4(f2b(f1.x), f2b(f1.y), f2b(f1.z), f2b(f1.w));
        }
        __syncthreads();
        if (ks + 1 < NKS) {
            int ko = (ks + 1) * 32;
            if (IS_BF16) {
                u0 = make_ushort4(0, 0, 0, 0); u1 = u0;
                if (row0 + r0s < n) u0 = *(const ushort4*)&Xb[(size_t)(row0 + r0s) * K + ko + c0s];
                if (row0 + r1s < n) u1 = *(const ushort4*)&Xb[(size_t)(row0 + r1s) * K + ko + c1s];
            } else {
                f0 = make_float4(0.f, 0.f, 0.f, 0.f); f1 = f0;
                if (row0 + r0s < n) f0 = *(const float4*)&Xf[(size_t)(row0 + r0s) * K + ko + c0s];
                if (row0 + r1s < n) f1 = *(const float4*)&Xf[(size_t)(row0 + r1s) * K + ko + c1s];
            }
        }
#pragma unroll
        for (int fm = 0; fm < 4; ++fm) {
            bf16x8 afr = *(const bf16x8*)&As[(fm * 16 + lr) * 40 + lg * 8];
#pragma unroll
            for (int fn = 0; fn < 2; ++fn)
                acc[fm][fn] = __builtin_amdgcn_mfma_f32_16x16x32_bf16(
                    afr, bfr[ks][fn], acc[fm][fn], 0, 0, 0);
        }
    }
#pragma unroll
    for (int fm = 0; fm < 4; ++fm) {
#pragma unroll
        for (int r = 0; r < 4; ++r) {
            int gr = row0 + fm * 16 + lg * 4 + r;
            if (gr < n) {
#pragma unroll
                for (int fn = 0; fn < 2; ++fn)
                    Hb[(size_t)gr * 128 + w * 32 + fn * 16 + lr] = f2b(acc[fm][fn][r]);
            }
        }
    }
}

// ---------------- fused: gemm1 (blocks < NB_G1) || padded-CSR fill (rest) ----------------
// Fill waves get raised priority (s_setprio): they're the long pole (L2-atomic
// throughput); priority biases CU issue slots toward the atomic stream while
// gemm waves absorb leftover VALU/MFMA slots.
__global__ __launch_bounds__(256) void k_fused1(const float* __restrict__ x,
                                                const unsigned short* __restrict__ Wt1,
                                                unsigned short* __restrict__ bufA,
                                                const int* __restrict__ src,
                                                const int* __restrict__ dst,
                                                int* __restrict__ counts,
                                                int* __restrict__ col_p, int nE4) {
    __shared__ unsigned short As[64 * 40];
    const int b = blockIdx.x, tid = threadIdx.x;
    if (b < NB_G1) {
        gemm_body<EMBED, false>(b, tid, x, Wt1, bufA, N_NODES, As);
        return;
    }
    int g = b & (NPART - 1);
    int i = ((b - NB_G1) >> 3) * 256 + tid;
    if (i >= nE4) return;
    __builtin_amdgcn_s_setprio(1);
    intx4 d4 = *(const intx4*)&dst[i * 4];
    intx4 s4 = *(const intx4*)&src[i * 4];
#pragma unroll
    for (int q = 0; q < 4; ++q) {
        int d = d4[q];
        if ((unsigned)(d - g * NODES_PER_PART) < (unsigned)NODES_PER_PART) {
            int pos = atomicAdd(&counts[d], 1);
            if (pos < RCAP) col_p[d * RCAP + pos] = s4[q];
        }
    }
    __builtin_amdgcn_s_setprio(0);
}

// gemm2 standalone
__global__ __launch_bounds__(256) void k_gemm2(const unsigned short* __restrict__ X,
                                               const unsigned short* __restrict__ Wt,
                                               unsigned short* __restrict__ Hb, int n) {
    __shared__ unsigned short As[64 * 40];
    gemm_body<HID, true>(blockIdx.x, threadIdx.x, X, Wt, Hb, n, As);
}

// ---------------- 64-lane bitonic sort of one padded row -> LDS ----------------
// col_p stays unsorted globally; every reader sorts identically (comparison sort on
// the same multiset -> identical sorted keys) => FP sum order deterministic.
__device__ __forceinline__ void sort_row_to_lds(const int* __restrict__ col_p,
                                                int v, int cnt, int lane64,
                                                int* __restrict__ srow) {
    int key = 0x7FFFFFFF;
    if (lane64 < cnt) key = col_p[v * RCAP + lane64];
#pragma unroll
    for (int k = 2; k <= 64; k <<= 1) {
#pragma unroll
        for (int j = k >> 1; j > 0; j >>= 1) {
            int other = __shfl_xor(key, j);
            bool up = ((lane64 & k) == 0);
            bool lower = ((lane64 & j) == 0);
            key = (lower == up) ? min(key, other) : max(key, other);
        }
    }
    srow[lane64] = key;
}

// ---------------- shared agg core: LDS col row, on-the-fly dinv ----------------
__device__ __forceinline__ f32x4 agg_core(const unsigned short* __restrict__ h,
                                          const int* __restrict__ counts,
                                          const int* __restrict__ srow,
                                          int v, int cnt, int lane, float dv) {
    ushort4 hv = *(const ushort4*)&h[(size_t)v * HID + lane * 4];
    float sl = dv * dv;
    f32x4 a0 = {b2f(hv.x) * sl, b2f(hv.y) * sl, b2f(hv.z) * sl, b2f(hv.w) * sl};
    f32x4 a1 = {0.f, 0.f, 0.f, 0.f}, a2 = a1, a3 = a1;
    for (int j0 = 0; j0 < cnt; j0 += 32) {
        int m = cnt - j0; if (m > 32) m = 32;
        int sj = 0; float wj = 0.f;                 // lanes >= m: w=0 -> exact no-op FMA
        if (lane < m) {
            sj = srow[j0 + lane];                   // LDS (sorted)
            wj = rsqrtf(1.0f + (float)counts[sj]) * dv;
        }
        int M = (m + 3) & ~3;
        float w0 = __shfl(wj, 0, 32), w1 = __shfl(wj, 1, 32);
        float w2 = __shfl(wj, 2, 32), w3 = __shfl(wj, 3, 32);
        int s0 = __shfl(sj, 0, 32), s1 = __shfl(sj, 1, 32);
        int s2 = __shfl(sj, 2, 32), s3 = __shfl(sj, 3, 32);
        ushort4 q0 = *(const ushort4*)&h[(size_t)s0 * HID + lane * 4];
        ushort4 q1 = *(const ushort4*)&h[(size_t)s1 * HID + lane * 4];
        ushort4 q2 = *(const ushort4*)&h[(size_t)s2 * HID + lane * 4];
        ushort4 q3 = *(const ushort4*)&h[(size_t)s3 * HID + lane * 4];
        for (int jj = 0; jj < M; jj += 4) {
            ushort4 n0 = q0, n1 = q1, n2 = q2, n3 = q3;
            float nw0 = 0.f, nw1 = 0.f, nw2 = 0.f, nw3 = 0.f;
            if (jj + 4 < M) {
                int t0 = __shfl(sj, jj + 4, 32), t1 = __shfl(sj, jj + 5, 32);
                int t2 = __shfl(sj, jj + 6, 32), t3 = __shfl(sj, jj + 7, 32);
                nw0 = __shfl(wj, jj + 4, 32); nw1 = __shfl(wj, jj + 5, 32);
                nw2 = __shfl(wj, jj + 6, 32); nw3 = __shfl(wj, jj + 7, 32);
                n0 = *(const ushort4*)&h[(size_t)t0 * HID + lane * 4];
                n1 = *(const ushort4*)&h[(size_t)t1 * HID + lane * 4];
                n2 = *(const ushort4*)&h[(size_t)t2 * HID + lane * 4];
                n3 = *(const ushort4*)&h[(size_t)t3 * HID + lane * 4];
            }
            a0[0] = fmaf(b2f(q0.x), w0, a0[0]); a0[1] = fmaf(b2f(q0.y), w0, a0[1]);
            a0[2] = fmaf(b2f(q0.z), w0, a0[2]); a0[3] = fmaf(b2f(q0.w), w0, a0[3]);
            a1[0] = fmaf(b2f(q1.x), w1, a1[0]); a1[1] = fmaf(b2f(q1.y), w1, a1[1]);
            a1[2] = fmaf(b2f(q1.z), w1, a1[2]); a1[3] = fmaf(b2f(q1.w), w1, a1[3]);
            a2[0] = fmaf(b2f(q2.x), w2, a2[0]); a2[1] = fmaf(b2f(q2.y), w2, a2[1]);
            a2[2] = fmaf(b2f(q2.z), w2, a2[2]); a2[3] = fmaf(b2f(q2.w), w2, a2[3]);
            a3[0] = fmaf(b2f(q3.x), w3, a3[0]); a3[1] = fmaf(b2f(q3.y), w3, a3[1]);
            a3[2] = fmaf(b2f(q3.z), w3, a3[2]); a3[3] = fmaf(b2f(q3.w), w3, a3[3]);
            q0 = n0; q1 = n1; q2 = n2; q3 = n3;
            w0 = nw0; w1 = nw1; w2 = nw2; w3 = nw3;
        }
    }
    f32x4 r;
    r[0] = (a0[0] + a1[0]) + (a2[0] + a3[0]);
    r[1] = (a0[1] + a1[1]) + (a2[1] + a3[1]);
    r[2] = (a0[2] + a1[2]) + (a2[2] + a3[2]);
    r[3] = (a0[3] + a1[3]) + (a2[3] + a3[3]);
    return r;
}

// layer-1: aggregate ALL nodes (8 nodes/block; in-kernel row sort)
__global__ __launch_bounds__(256) void k_agg_all(const unsigned short* __restrict__ h,
                                                 const int* __restrict__ counts,
                                                 const int* __restrict__ col_p,
                                                 const float* __restrict__ b,
                                                 unsigned short* __restrict__ out) {
    __shared__ int scol[8][64];
    const int tid = threadIdx.x;
    const int w = tid >> 6, lane64 = tid & 63;
    const int base = blockIdx.x * 8;
#pragma unroll
    for (int s = 0; s < 2; ++s) {
        int v = base + w * 2 + s;                       // < 50000 always (6250*8)
        int cnt = min(counts[v], RCAP);
        sort_row_to_lds(col_p, v, cnt, lane64, scol[w * 2 + s]);
    }
    __syncthreads();
    const int hw = tid >> 5, lane = tid & 31;
    const int v = base + hw;
    int cnt = min(counts[v], RCAP);
    float dv = rsqrtf(1.0f + (float)counts[v]);
    f32x4 a = agg_core(h, counts, scol[hw], v, cnt, lane, dv);
    float4 bv = *(const float4*)&b[lane * 4];
    ushort4 r;
    r.x = f2b(fmaxf(a[0] + bv.x, 0.f));
    r.y = f2b(fmaxf(a[1] + bv.y, 0.f));
    r.z = f2b(fmaxf(a[2] + bv.z, 0.f));
    r.w = f2b(fmaxf(a[3] + bv.w, 0.f));
    *(ushort4*)&out[(size_t)v * HID + lane * 4] = r;
}

// layer-2 + readout fused: 8 targets/block; in-kernel row sort; dot Wr; write pred
__global__ __launch_bounds__(256) void k_agg_tgt_final(const unsigned short* __restrict__ h,
                                                       const int* __restrict__ counts,
                                                       const int* __restrict__ col_p,
                                                       const int* __restrict__ tgt,
                                                       const float* __restrict__ b,
                                                       const float* __restrict__ Wr,
                                                       const float* __restrict__ br,
                                                       float* __restrict__ out) {
    __shared__ int scol[8][64];
    const int tid = threadIdx.x;
    const int w = tid >> 6, lane64 = tid & 63;
    const int base = blockIdx.x * 8;
#pragma unroll
    for (int s = 0; s < 2; ++s) {
        int v = tgt[base + w * 2 + s];                  // base+.. < 4096 always (512*8)
        int cnt = min(counts[v], RCAP);
        sort_row_to_lds(col_p, v, cnt, lane64, scol[w * 2 + s]);
    }
    __syncthreads();
    const int hw = tid >> 5, lane = tid & 31;
    const int tt = base + hw;
    const int v = tgt[tt];
    int cnt = min(counts[v], RCAP);
    float dv = rsqrtf(1.0f + (float)counts[v]);
    f32x4 a = agg_core(h, counts, scol[hw], v, cnt, lane, dv);
    float4 bv = *(const float4*)&b[lane * 4];
    float r0 = fmaxf(a[0] + bv.x, 0.f);
    float r1 = fmaxf(a[1] + bv.y, 0.f);
    float r2 = fmaxf(a[2] + bv.z, 0.f);
    float r3 = fmaxf(a[3] + bv.w, 0.f);
    const float* wr = &Wr[lane * 4 * OUTD];
#pragma unroll
    for (int j = 0; j < OUTD; ++j) {
        float p = r0 * wr[0 * OUTD + j] + r1 * wr[1 * OUTD + j] +
                  r2 * wr[2 * OUTD + j] + r3 * wr[3 * OUTD + j];
#pragma unroll
        for (int off = 16; off > 0; off >>= 1) p += __shfl_down(p, off, 32);
        if (lane == 0) out[tt * OUTD + j] = p + br[j];
    }
}

extern "C" void kernel_launch(void* const* d_in, const int* in_sizes, int n_in,
                              void* d_out, int out_size, void* d_ws, size_t ws_size,
                              hipStream_t stream) {
    const float* x  = (const float*)d_in[0];
    const int*   ei = (const int*)d_in[1];
    const int*   tm = (const int*)d_in[2];
    const float* W1 = (const float*)d_in[3];
    const float* b1 = (const float*)d_in[4];
    const float* W2 = (const float*)d_in[5];
    const float* b2 = (const float*)d_in[6];
    const float* Wr = (const float*)d_in[7];
    const float* br = (const float*)d_in[8];
    float* out = (float*)d_out;

    const int* e_src = ei;
    const int* e_dst = ei + N_EDGES;

    // workspace layout — all ranges disjoint:
    //   counts [0x040000, +200KB)
    //   Wt1 [0x380000)  Wt2 [0x390000)
    //   col_p [0x400000, +12.8MB)  bufA [0x1100000, +12.8MB)  bufB [0x1E00000, +12.8MB)
    char* ws = (char*)d_ws;
    int*            counts = (int*)  (ws + 0x040000);
    unsigned short* Wt1    = (unsigned short*)(ws + 0x380000);
    unsigned short* Wt2    = (unsigned short*)(ws + 0x390000);
    int*            col_p  = (int*)  (ws + 0x400000);
    unsigned short* bufA   = (unsigned short*)(ws + 0x1100000);
    unsigned short* bufB   = (unsigned short*)(ws + 0x1E00000);

    const int NE4     = N_EDGES / 4;                     // 200000
    const int NB_FILL = ((NE4 + 255) / 256) * NPART;     // 6256
    const int NB_F1   = NB_G1 + NB_FILL;                 // gemm first (measured best)
    const int NB_AGG  = N_NODES / 8;                     // 6250 (exact)
    const int NB_AGT  = N_TGT / 8;                       // 512 (exact)

    // ---- prelude, then fused {gemm1 || CSR fill (prioritized)} ----
    k_prelude<<<SCAN_NB, 256, 0, stream>>>(counts, W1, Wt1, W2, Wt2);
    k_fused1<<<NB_F1, 256, 0, stream>>>(x, Wt1, bufA, e_src, e_dst, counts, col_p, NE4);

    // ---- layer 1 agg (sorts rows in-kernel) ----
    k_agg_all<<<NB_AGG, 256, 0, stream>>>(bufA, counts, col_p, b1, bufB);

    // ---- layer 2 gemm, then fused {target agg + readout} ----
    k_gemm2<<<NB_G1, 256, 0, stream>>>(bufB, Wt2, bufA, N_NODES);
    k_agg_tgt_final<<<NB_AGT, 256, 0, stream>>>(bufA, counts, col_p, tm, b2, Wr, br, out);
}